// Round 10
// baseline (139.845 us; speedup 1.0000x reference)
//
#include <hip/hip_runtime.h>
#include <hip/hip_bf16.h>

#define NFEAT 128

typedef short bf16x8 __attribute__((ext_vector_type(8)));   // 8 bf16 as i16
typedef float f32x4  __attribute__((ext_vector_type(4)));
typedef float f32x8  __attribute__((ext_vector_type(8)));
typedef unsigned short u16x8 __attribute__((ext_vector_type(8)));

static __device__ __forceinline__ short f2bf(float f) {
    __hip_bfloat16 h = __float2bfloat16(f);   // round-to-nearest
    return __builtin_bit_cast(short, h);
}
static __device__ __forceinline__ float bf2f(unsigned short u) {
    unsigned int x = ((unsigned int)u) << 16;
    return __builtin_bit_cast(float, x);
}

// ---------------------------------------------------------------------------
// Fast zero of counts (int4-wide).
// ---------------------------------------------------------------------------
__global__ __launch_bounds__(256) void zero_counts(int4* __restrict__ p, int n4)
{
    const int i = blockIdx.x * 256 + threadIdx.x;
    if (i < n4) p[i] = make_int4(0, 0, 0, 0);
}

// ---------------------------------------------------------------------------
// Fused GEMM: g = (relu(X @ Wm^T + bm)) @ Wo^T, bf16 out.
// 64 rows/block (grid 1563 -> ~6 blocks/CU, TLP replaces prefetch pipeline).
// Block = 256 thr = 4 waves; wave w owns cols [32w,32w+32) over all 64 rows.
// B1/B2 reg-resident (64 VGPR). X staged cooperatively (NT loads, read-once)
// into 16 KB LDS as bf16 with granule-XOR swizzle:
//   elem (row,col) at row*128 + ((col>>3)^(row&15))*8 + (col&7)
// h-tile overwrites the consumed X buffer (barrier-fenced). 3 barriers.
// ---------------------------------------------------------------------------
__global__ __launch_bounds__(256) void gemm_fused(
    const float* __restrict__ X, const short* __restrict__ Wm,
    const float* __restrict__ bm, const short* __restrict__ Wo,
    short* __restrict__ G, int n)
{
    __shared__ short xb[64 * NFEAT];   // 16 KB
    const int t  = threadIdx.x;
    const int w  = t >> 6;
    const int l  = t & 63;
    const int lr = l & 15;
    const int lk = l >> 4;
    const int row0 = blockIdx.x * 64;
    const int colw = w * 32;

    // B operands into registers (per-wave 32-col slice of Wm and Wo)
    bf16x8 b1[2][4], b2[2][4];
#pragma unroll
    for (int c2 = 0; c2 < 2; ++c2)
#pragma unroll
        for (int k0 = 0; k0 < 4; ++k0) {
            const size_t off = (size_t)(colw + c2 * 16 + lr) * NFEAT + k0 * 32 + lk * 8;
            b1[c2][k0] = *(const bf16x8*)(Wm + off);
            b2[c2][k0] = *(const bf16x8*)(Wo + off);
        }
    const float bv0 = bm[colw + lr];
    const float bv1 = bm[colw + 16 + lr];

    // stage 64x128 X tile: NT float4 loads -> bf16 -> swizzled LDS
#pragma unroll
    for (int i = 0; i < 4; ++i) {
        const int row = min(row0 + i * 16 + (t >> 4), n - 1);
        const float* p = X + (size_t)row * NFEAT + (t & 15) * 8;
        const f32x4 x0 = __builtin_nontemporal_load((const f32x4*)p);
        const f32x4 x1 = __builtin_nontemporal_load((const f32x4*)(p + 4));
        const int rl = i * 16 + (t >> 4);
        const int g  = (t & 15) ^ (rl & 15);
        bf16x8 v;
        v[0] = f2bf(x0[0]); v[1] = f2bf(x0[1]); v[2] = f2bf(x0[2]); v[3] = f2bf(x0[3]);
        v[4] = f2bf(x1[0]); v[5] = f2bf(x1[1]); v[6] = f2bf(x1[2]); v[7] = f2bf(x1[3]);
        *(bf16x8*)(&xb[rl * NFEAT + g * 8]) = v;
    }
    __syncthreads();

    // GEMM1: h = relu(X @ Wm^T + bm)
    f32x4 acc[4][2];
#pragma unroll
    for (int rt = 0; rt < 4; ++rt) {
        acc[rt][0] = (f32x4){0.f, 0.f, 0.f, 0.f};
        acc[rt][1] = (f32x4){0.f, 0.f, 0.f, 0.f};
    }
#pragma unroll
    for (int rt = 0; rt < 4; ++rt) {
        bf16x8 a[4];
#pragma unroll
        for (int k0 = 0; k0 < 4; ++k0)
            a[k0] = *(const bf16x8*)(xb + (rt * 16 + lr) * NFEAT + ((k0 * 4 + lk) ^ lr) * 8);
#pragma unroll
        for (int k0 = 0; k0 < 4; ++k0) {
            acc[rt][0] = __builtin_amdgcn_mfma_f32_16x16x32_bf16(a[k0], b1[0][k0], acc[rt][0], 0, 0, 0);
            acc[rt][1] = __builtin_amdgcn_mfma_f32_16x16x32_bf16(a[k0], b1[1][k0], acc[rt][1], 0, 0, 0);
        }
    }
    __syncthreads();   // all A-reads done before h overwrites xb

    // h-write (bias+relu) into same swizzled layout
#pragma unroll
    for (int rt = 0; rt < 4; ++rt)
#pragma unroll
        for (int c2 = 0; c2 < 2; ++c2) {
            const int col = colw + c2 * 16 + lr;
            const int gc  = col >> 3;
            const float bv = c2 ? bv1 : bv0;
#pragma unroll
            for (int r = 0; r < 4; ++r) {
                const int row = rt * 16 + lk * 4 + r;
                const float v = fmaxf(acc[rt][c2][r] + bv, 0.f);
                xb[row * NFEAT + (gc ^ (row & 15)) * 8 + (col & 7)] = f2bf(v);
            }
        }
    __syncthreads();   // h visible

    // GEMM2: g = h @ Wo^T, store bf16
#pragma unroll
    for (int rt = 0; rt < 4; ++rt) {
        bf16x8 a[4];
#pragma unroll
        for (int k0 = 0; k0 < 4; ++k0)
            a[k0] = *(const bf16x8*)(xb + (rt * 16 + lr) * NFEAT + ((k0 * 4 + lk) ^ lr) * 8);
        f32x4 c0 = (f32x4){0.f, 0.f, 0.f, 0.f};
        f32x4 c1 = (f32x4){0.f, 0.f, 0.f, 0.f};
#pragma unroll
        for (int k0 = 0; k0 < 4; ++k0) {
            c0 = __builtin_amdgcn_mfma_f32_16x16x32_bf16(a[k0], b2[0][k0], c0, 0, 0, 0);
            c1 = __builtin_amdgcn_mfma_f32_16x16x32_bf16(a[k0], b2[1][k0], c1, 0, 0, 0);
        }
#pragma unroll
        for (int c2 = 0; c2 < 2; ++c2) {
            const int col = colw + c2 * 16 + lr;
#pragma unroll
            for (int r = 0; r < 4; ++r) {
                const int orow = row0 + rt * 16 + lk * 4 + r;
                const float v = c2 ? c1[r] : c0[r];
                if (orow < n) G[(size_t)orow * NFEAT + col] = f2bf(v);
            }
        }
    }
}

// ---------------------------------------------------------------------------
// CSR build: convert weights (first 64 blocks) + degree count, 4 edges/thread.
// ---------------------------------------------------------------------------
__global__ __launch_bounds__(256) void convert_and_count(
    const float* __restrict__ wa, const float* __restrict__ wb,
    short* __restrict__ oa, short* __restrict__ ob,
    const int* __restrict__ dst, int* __restrict__ counts, int nE)
{
    const int tid = blockIdx.x * 256 + threadIdx.x;
    if (tid < NFEAT * NFEAT / 4) {
        const f32x4 a = *(const f32x4*)(wa + tid * 4);
        const f32x4 b = *(const f32x4*)(wb + tid * 4);
        short4 sa, sb;
        sa.x = f2bf(a[0]); sa.y = f2bf(a[1]); sa.z = f2bf(a[2]); sa.w = f2bf(a[3]);
        sb.x = f2bf(b[0]); sb.y = f2bf(b[1]); sb.z = f2bf(b[2]); sb.w = f2bf(b[3]);
        *(short4*)(oa + tid * 4) = sa;
        *(short4*)(ob + tid * 4) = sb;
    }
    const int i0 = tid * 4;
    if (i0 + 4 <= nE) {
        const int4 d4 = *(const int4*)(dst + i0);
        atomicAdd(&counts[d4.x], 1);
        atomicAdd(&counts[d4.y], 1);
        atomicAdd(&counts[d4.z], 1);
        atomicAdd(&counts[d4.w], 1);
    } else {
        for (int i = i0; i < nE; ++i) atomicAdd(&counts[dst[i]], 1);
    }
}

__global__ __launch_bounds__(256) void scan_block(
    const int* __restrict__ counts, int* __restrict__ offsets,
    int* __restrict__ blocksums, int n)
{
    __shared__ int s[256];
    const int t = threadIdx.x;
    const int i = blockIdx.x * 256 + t;
    const int v = (i < n) ? counts[i] : 0;
    s[t] = v;
    __syncthreads();
    for (int off = 1; off < 256; off <<= 1) {
        const int add = (t >= off) ? s[t - off] : 0;
        __syncthreads();
        s[t] += add;
        __syncthreads();
    }
    if (i < n) offsets[i] = s[t] - v;
    if (t == 255) blocksums[blockIdx.x] = s[255];
}

// Each block redundantly reduces blocksums[0..blockIdx) then offsets += base.
__global__ __launch_bounds__(256) void add_offsets(
    int* __restrict__ offsets, int* __restrict__ cursor,
    const int* __restrict__ blocksums, int n)
{
    __shared__ int red[256];
    int partial = 0;
    for (int j = threadIdx.x; j < blockIdx.x; j += 256) partial += blocksums[j];
    red[threadIdx.x] = partial;
    __syncthreads();
    for (int s = 128; s > 0; s >>= 1) {
        if (threadIdx.x < s) red[threadIdx.x] += red[threadIdx.x + s];
        __syncthreads();
    }
    const int base = red[0];
    const int i = blockIdx.x * 256 + threadIdx.x;
    if (i < n) {
        const int o = offsets[i] + base;
        offsets[i] = o;
        cursor[i] = o;
    }
}

// ---------------------------------------------------------------------------
// Edge fill, 4 edges/thread (int4 loads, 4 independent atomic+store chains).
// ---------------------------------------------------------------------------
__global__ __launch_bounds__(256) void fill_edges(
    const int* __restrict__ src, const int* __restrict__ dst,
    int* __restrict__ cursor, int* __restrict__ esrc, int nE)
{
    const int i0 = (blockIdx.x * 256 + threadIdx.x) * 4;
    if (i0 + 4 <= nE) {
        const int4 s4 = *(const int4*)(src + i0);
        const int4 d4 = *(const int4*)(dst + i0);
        const int p0 = atomicAdd(&cursor[d4.x], 1);
        const int p1 = atomicAdd(&cursor[d4.y], 1);
        const int p2 = atomicAdd(&cursor[d4.z], 1);
        const int p3 = atomicAdd(&cursor[d4.w], 1);
        esrc[p0] = s4.x; esrc[p1] = s4.y; esrc[p2] = s4.z; esrc[p3] = s4.w;
    } else {
        for (int i = i0; i < nE; ++i) {
            const int p = atomicAdd(&cursor[dst[i]], 1);
            esrc[p] = src[i];
        }
    }
}

// ---------------------------------------------------------------------------
// out[d] = b_out + sum_{e: dst=d} g[src[e]]   (g bf16, out f32).
// 16 lanes x ushort8 (16 B) per node; 16 nodes per 256-thread block.
// 4-edge unroll -> 4 outstanding 16B gathers per lane.
// ---------------------------------------------------------------------------
__global__ __launch_bounds__(256) void gather_sum(
    const unsigned short* __restrict__ g, const int* __restrict__ offsets,
    const int* __restrict__ cursor, const int* __restrict__ esrc,
    const float* __restrict__ bias, float* __restrict__ out, int nNodes)
{
    const int node = blockIdx.x * 16 + (threadIdx.x >> 4);
    const int lf = threadIdx.x & 15;
    if (node >= nNodes) return;

    float acc[8];
    {
        const float4 b0 = *(const float4*)(bias + lf * 8);
        const float4 b1 = *(const float4*)(bias + lf * 8 + 4);
        acc[0] = b0.x; acc[1] = b0.y; acc[2] = b0.z; acc[3] = b0.w;
        acc[4] = b1.x; acc[5] = b1.y; acc[6] = b1.z; acc[7] = b1.w;
    }

    const int beg = offsets[node];
    const int end = cursor[node];
    int i = beg;
    for (; i + 4 <= end; i += 4) {
        const int s0 = __builtin_nontemporal_load(esrc + i);
        const int s1 = __builtin_nontemporal_load(esrc + i + 1);
        const int s2 = __builtin_nontemporal_load(esrc + i + 2);
        const int s3 = __builtin_nontemporal_load(esrc + i + 3);
        const u16x8 v0 = *(const u16x8*)(g + (size_t)s0 * NFEAT + lf * 8);
        const u16x8 v1 = *(const u16x8*)(g + (size_t)s1 * NFEAT + lf * 8);
        const u16x8 v2 = *(const u16x8*)(g + (size_t)s2 * NFEAT + lf * 8);
        const u16x8 v3 = *(const u16x8*)(g + (size_t)s3 * NFEAT + lf * 8);
#pragma unroll
        for (int j = 0; j < 8; ++j)
            acc[j] += (bf2f(v0[j]) + bf2f(v1[j])) + (bf2f(v2[j]) + bf2f(v3[j]));
    }
    for (; i < end; ++i) {
        const int s0 = __builtin_nontemporal_load(esrc + i);
        const u16x8 v0 = *(const u16x8*)(g + (size_t)s0 * NFEAT + lf * 8);
#pragma unroll
        for (int j = 0; j < 8; ++j) acc[j] += bf2f(v0[j]);
    }

    float* op = out + (size_t)node * NFEAT + lf * 8;
    const f32x4 o0 = (f32x4){acc[0], acc[1], acc[2], acc[3]};
    const f32x4 o1 = (f32x4){acc[4], acc[5], acc[6], acc[7]};
    __builtin_nontemporal_store(o0, (f32x4*)op);
    __builtin_nontemporal_store(o1, (f32x4*)(op + 4));
}

extern "C" void kernel_launch(void* const* d_in, const int* in_sizes, int n_in,
                              void* d_out, int out_size, void* d_ws, size_t ws_size,
                              hipStream_t stream) {
    const float* node_feats = (const float*)d_in[0];
    const int*   src        = (const int*)d_in[1];
    const int*   dst        = (const int*)d_in[2];
    const float* W_msg      = (const float*)d_in[3];
    const float* b_msg      = (const float*)d_in[4];
    const float* W_out      = (const float*)d_in[5];
    const float* b_out      = (const float*)d_in[6];

    const int nNodes = in_sizes[0] / NFEAT;
    const int nEdges = in_sizes[1];

    float* out = (float*)d_out;

    // ws layout: gbf | wm_bf | wo_bf | counts | offsets | cursor | blocksums | esrc
    short* gbf      = (short*)d_ws;                                  // nNodes*128 bf16
    short* wm_bf    = gbf + (size_t)nNodes * NFEAT;                  // 16384 bf16
    short* wo_bf    = wm_bf + NFEAT * NFEAT;                         // 16384 bf16
    int*   counts   = (int*)(wo_bf + NFEAT * NFEAT);                 // nNodes
    int*   offsets  = counts + nNodes;                               // nNodes
    int*   cursor   = offsets + nNodes;                              // nNodes
    int*   blocksums= cursor + nNodes;                               // 512
    int*   esrc     = blocksums + 512;                               // nEdges

    const int nb1 = (nNodes + 255) / 256;   // 391
    const int nbq = (nEdges + 1023) / 1024; // 625 (4 edges/thread)
    const int ngb = (nNodes + 63) / 64;     // 1563
    const int n4  = (nNodes + 3) / 4;

    // --- CSR build (+ weight conversion piggybacked) ---
    zero_counts<<<(n4 + 255) / 256, 256, 0, stream>>>((int4*)counts, n4);
    convert_and_count<<<nbq, 256, 0, stream>>>(W_msg, W_out, wm_bf, wo_bf, dst, counts, nEdges);
    scan_block<<<nb1, 256, 0, stream>>>(counts, offsets, blocksums, nNodes);
    add_offsets<<<nb1, 256, 0, stream>>>(offsets, cursor, blocksums, nNodes);
    fill_edges<<<nbq, 256, 0, stream>>>(src, dst, cursor, esrc, nEdges);

    // --- g = relu(X @ Wm^T + bm) @ Wo^T  [bf16, fused, 64-row blocks] ---
    gemm_fused<<<ngb, 256, 0, stream>>>(node_feats, wm_bf, b_msg, wo_bf, gbf, nNodes);

    // --- out[d] = b_out + sum g[src[e]] ---
    gather_sum<<<(nNodes + 15) / 16, 256, 0, stream>>>(
        (const unsigned short*)gbf, offsets, cursor, esrc, b_out, out, nNodes);
}

// Round 11
// 130.810 us; speedup vs baseline: 1.0691x; 1.0691x over previous
//
#include <hip/hip_runtime.h>
#include <hip/hip_bf16.h>

#define NFEAT 128

typedef short bf16x8 __attribute__((ext_vector_type(8)));   // 8 bf16 as i16
typedef float f32x4  __attribute__((ext_vector_type(4)));
typedef unsigned short u16x8 __attribute__((ext_vector_type(8)));

static __device__ __forceinline__ short f2bf(float f) {
    __hip_bfloat16 h = __float2bfloat16(f);   // round-to-nearest
    return __builtin_bit_cast(short, h);
}
static __device__ __forceinline__ float bf2f(unsigned short u) {
    unsigned int x = ((unsigned int)u) << 16;
    return __builtin_bit_cast(float, x);
}

// ---------------------------------------------------------------------------
// Fast zero of counts (int4-wide).
// ---------------------------------------------------------------------------
__global__ __launch_bounds__(256) void zero_counts(int4* __restrict__ p, int n4)
{
    const int i = blockIdx.x * 256 + threadIdx.x;
    if (i < n4) p[i] = make_int4(0, 0, 0, 0);
}

// ---------------------------------------------------------------------------
// Fused GEMM: g = (relu(X @ Wm^T + bm)) @ Wo^T, bf16 out.
// R9's verified 2-panel/128-row structure, widened to 512 thr = 8 waves:
// wave w owns cols [16w,16w+16) -> B1/B2 = 32 VGPR total; grid stays 782
// but each block is 8 waves -> ~16 waves/CU resident (was 12).
// X panel staged cooperatively into LDS as bf16, granule-XOR swizzle:
//   elem (row,col) at row*128 + ((col>>3)^(row&15))*8 + (col&7)
// Panel-1 loads prefetched before panel-0 GEMM1 (T14); h-tile overwrites
// consumed X buffer. 2 barriers/panel.
// ---------------------------------------------------------------------------
__global__ __launch_bounds__(512, 4) void gemm_fused(
    const float* __restrict__ X, const short* __restrict__ Wm,
    const float* __restrict__ bm, const short* __restrict__ Wo,
    short* __restrict__ G, int n)
{
    __shared__ short xb[2][64 * NFEAT];   // 2 x 16 KB
    const int t  = threadIdx.x;
    const int w  = t >> 6;        // 0..7
    const int l  = t & 63;
    const int lr = l & 15;
    const int lk = l >> 4;
    const int row0 = blockIdx.x * 128;
    const int colw = w * 16;
    const int col  = colw + lr;   // this lane's output column

    // B operands into registers (per-wave 16-col slice of Wm and Wo)
    bf16x8 b1[4], b2[4];
#pragma unroll
    for (int k0 = 0; k0 < 4; ++k0) {
        const size_t off = (size_t)col * NFEAT + k0 * 32 + lk * 8;
        b1[k0] = *(const bf16x8*)(Wm + off);
        b2[k0] = *(const bf16x8*)(Wo + off);
    }
    const float bv = bm[col];

    // staging geometry: thread t covers rows (t>>4) and (t>>4)+32, col-group t&15
    const int sr = t >> 4;        // 0..31
    const int cg = t & 15;

    // ---- stage panel 0 ----
    float4 pf[4];
    {
        const int ra = min(row0 + sr, n - 1);
        const int rb = min(row0 + sr + 32, n - 1);
        const float* pa = X + (size_t)ra * NFEAT + cg * 8;
        const float* pb = X + (size_t)rb * NFEAT + cg * 8;
        pf[0] = *(const float4*)pa; pf[1] = *(const float4*)(pa + 4);
        pf[2] = *(const float4*)pb; pf[3] = *(const float4*)(pb + 4);
    }
    {
        const int g0 = cg ^ (sr & 15);
        bf16x8 v;
        v[0] = f2bf(pf[0].x); v[1] = f2bf(pf[0].y); v[2] = f2bf(pf[0].z); v[3] = f2bf(pf[0].w);
        v[4] = f2bf(pf[1].x); v[5] = f2bf(pf[1].y); v[6] = f2bf(pf[1].z); v[7] = f2bf(pf[1].w);
        *(bf16x8*)(&xb[0][sr * NFEAT + g0 * 8]) = v;
        const int r2 = sr + 32;
        const int g2 = cg ^ (r2 & 15);
        v[0] = f2bf(pf[2].x); v[1] = f2bf(pf[2].y); v[2] = f2bf(pf[2].z); v[3] = f2bf(pf[2].w);
        v[4] = f2bf(pf[3].x); v[5] = f2bf(pf[3].y); v[6] = f2bf(pf[3].z); v[7] = f2bf(pf[3].w);
        *(bf16x8*)(&xb[1 - 1][r2 * NFEAT + g2 * 8]) = v;   // xb[0]
    }
    __syncthreads();

#pragma unroll
    for (int p = 0; p < 2; ++p) {
        short* cur = &xb[p][0];

        // prefetch panel 1 global loads before panel-0 compute
        if (p == 0) {
            const int ra = min(row0 + 64 + sr, n - 1);
            const int rb = min(row0 + 64 + sr + 32, n - 1);
            const float* pa = X + (size_t)ra * NFEAT + cg * 8;
            const float* pb = X + (size_t)rb * NFEAT + cg * 8;
            pf[0] = *(const float4*)pa; pf[1] = *(const float4*)(pa + 4);
            pf[2] = *(const float4*)pb; pf[3] = *(const float4*)(pb + 4);
        }

        // GEMM1: h = relu(X @ Wm^T + bm)
        f32x4 acc[4];
#pragma unroll
        for (int rt = 0; rt < 4; ++rt) acc[rt] = (f32x4){0.f, 0.f, 0.f, 0.f};
#pragma unroll
        for (int rt = 0; rt < 4; ++rt) {
            bf16x8 a[4];
#pragma unroll
            for (int k0 = 0; k0 < 4; ++k0)
                a[k0] = *(const bf16x8*)(cur + (rt * 16 + lr) * NFEAT + ((k0 * 4 + lk) ^ lr) * 8);
#pragma unroll
            for (int k0 = 0; k0 < 4; ++k0)
                acc[rt] = __builtin_amdgcn_mfma_f32_16x16x32_bf16(a[k0], b1[k0], acc[rt], 0, 0, 0);
        }
        __syncthreads();   // all A-reads of cur done

        // h-write (bias+relu) overwrites cur; staged write of panel 1
        {
            const int gc = col >> 3;
#pragma unroll
            for (int rt = 0; rt < 4; ++rt)
#pragma unroll
                for (int r = 0; r < 4; ++r) {
                    const int row = rt * 16 + lk * 4 + r;
                    const float v = fmaxf(acc[rt][r] + bv, 0.f);
                    cur[row * NFEAT + (gc ^ (row & 15)) * 8 + (col & 7)] = f2bf(v);
                }
        }
        if (p == 0) {
            const int g0 = cg ^ (sr & 15);
            bf16x8 v;
            v[0] = f2bf(pf[0].x); v[1] = f2bf(pf[0].y); v[2] = f2bf(pf[0].z); v[3] = f2bf(pf[0].w);
            v[4] = f2bf(pf[1].x); v[5] = f2bf(pf[1].y); v[6] = f2bf(pf[1].z); v[7] = f2bf(pf[1].w);
            *(bf16x8*)(&xb[1][sr * NFEAT + g0 * 8]) = v;
            const int r2 = sr + 32;
            const int g2 = cg ^ (r2 & 15);
            v[0] = f2bf(pf[2].x); v[1] = f2bf(pf[2].y); v[2] = f2bf(pf[2].z); v[3] = f2bf(pf[2].w);
            v[4] = f2bf(pf[3].x); v[5] = f2bf(pf[3].y); v[6] = f2bf(pf[3].z); v[7] = f2bf(pf[3].w);
            *(bf16x8*)(&xb[1][r2 * NFEAT + g2 * 8]) = v;
        }
        __syncthreads();   // h (and next X) visible

        // GEMM2: g = h @ Wo^T, store bf16
#pragma unroll
        for (int rt = 0; rt < 4; ++rt) {
            bf16x8 a[4];
#pragma unroll
            for (int k0 = 0; k0 < 4; ++k0)
                a[k0] = *(const bf16x8*)(cur + (rt * 16 + lr) * NFEAT + ((k0 * 4 + lk) ^ lr) * 8);
            f32x4 c0 = (f32x4){0.f, 0.f, 0.f, 0.f};
#pragma unroll
            for (int k0 = 0; k0 < 4; ++k0)
                c0 = __builtin_amdgcn_mfma_f32_16x16x32_bf16(a[k0], b2[k0], c0, 0, 0, 0);
#pragma unroll
            for (int r = 0; r < 4; ++r) {
                const int orow = row0 + p * 64 + rt * 16 + lk * 4 + r;
                if (orow < n) G[(size_t)orow * NFEAT + col] = f2bf(c0[r]);
            }
        }
    }
}

// ---------------------------------------------------------------------------
// CSR build: convert weights (first 64 blocks) + degree count, one kernel.
// ---------------------------------------------------------------------------
__global__ __launch_bounds__(256) void convert_and_count(
    const float* __restrict__ wa, const float* __restrict__ wb,
    short* __restrict__ oa, short* __restrict__ ob,
    const int* __restrict__ dst, int* __restrict__ counts, int nE)
{
    const int i = blockIdx.x * 256 + threadIdx.x;
    if (i < NFEAT * NFEAT) { oa[i] = f2bf(wa[i]); ob[i] = f2bf(wb[i]); }
    if (i < nE) atomicAdd(&counts[dst[i]], 1);
}

__global__ __launch_bounds__(256) void scan_block(
    const int* __restrict__ counts, int* __restrict__ offsets,
    int* __restrict__ blocksums, int n)
{
    __shared__ int s[256];
    const int t = threadIdx.x;
    const int i = blockIdx.x * 256 + t;
    const int v = (i < n) ? counts[i] : 0;
    s[t] = v;
    __syncthreads();
    for (int off = 1; off < 256; off <<= 1) {
        const int add = (t >= off) ? s[t - off] : 0;
        __syncthreads();
        s[t] += add;
        __syncthreads();
    }
    if (i < n) offsets[i] = s[t] - v;
    if (t == 255) blocksums[blockIdx.x] = s[255];
}

// Each block redundantly reduces blocksums[0..blockIdx) then offsets += base.
__global__ __launch_bounds__(256) void add_offsets(
    int* __restrict__ offsets, int* __restrict__ cursor,
    const int* __restrict__ blocksums, int n)
{
    __shared__ int red[256];
    int partial = 0;
    for (int j = threadIdx.x; j < blockIdx.x; j += 256) partial += blocksums[j];
    red[threadIdx.x] = partial;
    __syncthreads();
    for (int s = 128; s > 0; s >>= 1) {
        if (threadIdx.x < s) red[threadIdx.x] += red[threadIdx.x + s];
        __syncthreads();
    }
    const int base = red[0];
    const int i = blockIdx.x * 256 + threadIdx.x;
    if (i < n) {
        const int o = offsets[i] + base;
        offsets[i] = o;
        cursor[i] = o;
    }
}

// ---------------------------------------------------------------------------
// Edge fill, 4 edges/thread (int4 loads, 4 independent atomic+store chains).
// ---------------------------------------------------------------------------
__global__ __launch_bounds__(256) void fill_edges(
    const int* __restrict__ src, const int* __restrict__ dst,
    int* __restrict__ cursor, int* __restrict__ esrc, int nE)
{
    const int i0 = (blockIdx.x * 256 + threadIdx.x) * 4;
    if (i0 + 4 <= nE) {
        const int4 s4 = *(const int4*)(src + i0);
        const int4 d4 = *(const int4*)(dst + i0);
        const int p0 = atomicAdd(&cursor[d4.x], 1);
        const int p1 = atomicAdd(&cursor[d4.y], 1);
        const int p2 = atomicAdd(&cursor[d4.z], 1);
        const int p3 = atomicAdd(&cursor[d4.w], 1);
        esrc[p0] = s4.x; esrc[p1] = s4.y; esrc[p2] = s4.z; esrc[p3] = s4.w;
    } else {
        for (int i = i0; i < nE; ++i) {
            const int p = atomicAdd(&cursor[dst[i]], 1);
            esrc[p] = src[i];
        }
    }
}

// ---------------------------------------------------------------------------
// out[d] = b_out + sum_{e: dst=d} g[src[e]]   (g bf16, out f32).
// 16 lanes x ushort8 (16 B) per node; 16 nodes per 256-thread block.
// 4-edge unroll -> 4 outstanding 16B gathers per lane.
// ---------------------------------------------------------------------------
__global__ __launch_bounds__(256) void gather_sum(
    const unsigned short* __restrict__ g, const int* __restrict__ offsets,
    const int* __restrict__ cursor, const int* __restrict__ esrc,
    const float* __restrict__ bias, float* __restrict__ out, int nNodes)
{
    const int node = blockIdx.x * 16 + (threadIdx.x >> 4);
    const int lf = threadIdx.x & 15;
    if (node >= nNodes) return;

    float acc[8];
    {
        const float4 b0 = *(const float4*)(bias + lf * 8);
        const float4 b1 = *(const float4*)(bias + lf * 8 + 4);
        acc[0] = b0.x; acc[1] = b0.y; acc[2] = b0.z; acc[3] = b0.w;
        acc[4] = b1.x; acc[5] = b1.y; acc[6] = b1.z; acc[7] = b1.w;
    }

    const int beg = offsets[node];
    const int end = cursor[node];
    int i = beg;
    for (; i + 4 <= end; i += 4) {
        const int s0 = __builtin_nontemporal_load(esrc + i);
        const int s1 = __builtin_nontemporal_load(esrc + i + 1);
        const int s2 = __builtin_nontemporal_load(esrc + i + 2);
        const int s3 = __builtin_nontemporal_load(esrc + i + 3);
        const u16x8 v0 = *(const u16x8*)(g + (size_t)s0 * NFEAT + lf * 8);
        const u16x8 v1 = *(const u16x8*)(g + (size_t)s1 * NFEAT + lf * 8);
        const u16x8 v2 = *(const u16x8*)(g + (size_t)s2 * NFEAT + lf * 8);
        const u16x8 v3 = *(const u16x8*)(g + (size_t)s3 * NFEAT + lf * 8);
#pragma unroll
        for (int j = 0; j < 8; ++j)
            acc[j] += (bf2f(v0[j]) + bf2f(v1[j])) + (bf2f(v2[j]) + bf2f(v3[j]));
    }
    for (; i < end; ++i) {
        const int s0 = __builtin_nontemporal_load(esrc + i);
        const u16x8 v0 = *(const u16x8*)(g + (size_t)s0 * NFEAT + lf * 8);
#pragma unroll
        for (int j = 0; j < 8; ++j) acc[j] += bf2f(v0[j]);
    }

    float* op = out + (size_t)node * NFEAT + lf * 8;
    const f32x4 o0 = (f32x4){acc[0], acc[1], acc[2], acc[3]};
    const f32x4 o1 = (f32x4){acc[4], acc[5], acc[6], acc[7]};
    __builtin_nontemporal_store(o0, (f32x4*)op);
    __builtin_nontemporal_store(o1, (f32x4*)(op + 4));
}

extern "C" void kernel_launch(void* const* d_in, const int* in_sizes, int n_in,
                              void* d_out, int out_size, void* d_ws, size_t ws_size,
                              hipStream_t stream) {
    const float* node_feats = (const float*)d_in[0];
    const int*   src        = (const int*)d_in[1];
    const int*   dst        = (const int*)d_in[2];
    const float* W_msg      = (const float*)d_in[3];
    const float* b_msg      = (const float*)d_in[4];
    const float* W_out      = (const float*)d_in[5];
    const float* b_out      = (const float*)d_in[6];

    const int nNodes = in_sizes[0] / NFEAT;
    const int nEdges = in_sizes[1];

    float* out = (float*)d_out;

    // ws layout: gbf | wm_bf | wo_bf | counts | offsets | cursor | blocksums | esrc
    short* gbf      = (short*)d_ws;                                  // nNodes*128 bf16
    short* wm_bf    = gbf + (size_t)nNodes * NFEAT;                  // 16384 bf16
    short* wo_bf    = wm_bf + NFEAT * NFEAT;                         // 16384 bf16
    int*   counts   = (int*)(wo_bf + NFEAT * NFEAT);                 // nNodes
    int*   offsets  = counts + nNodes;                               // nNodes
    int*   cursor   = offsets + nNodes;                              // nNodes
    int*   blocksums= cursor + nNodes;                               // 512
    int*   esrc     = blocksums + 512;                               // nEdges

    const int nb1 = (nNodes + 255) / 256;   // 391
    const int nbe = (nEdges + 255) / 256;   // 2500
    const int nbf = (nEdges + 1023) / 1024; // 625 (4 edges/thread)
    const int ngb = (nNodes + 127) / 128;   // 782
    const int n4  = (nNodes + 3) / 4;

    // --- CSR build (+ weight conversion piggybacked) ---
    zero_counts<<<(n4 + 255) / 256, 256, 0, stream>>>((int4*)counts, n4);
    convert_and_count<<<nbe, 256, 0, stream>>>(W_msg, W_out, wm_bf, wo_bf, dst, counts, nEdges);
    scan_block<<<nb1, 256, 0, stream>>>(counts, offsets, blocksums, nNodes);
    add_offsets<<<nb1, 256, 0, stream>>>(offsets, cursor, blocksums, nNodes);
    fill_edges<<<nbf, 256, 0, stream>>>(src, dst, cursor, esrc, nEdges);

    // --- g = relu(X @ Wm^T + bm) @ Wo^T  [bf16, fused, 2-panel, 8 waves] ---
    gemm_fused<<<ngb, 512, 0, stream>>>(node_feats, wm_bf, b_msg, wo_bf, gbf, nNodes);

    // --- out[d] = b_out + sum g[src[e]] ---
    gather_sum<<<(nNodes + 15) / 16, 256, 0, stream>>>(
        (const unsigned short*)gbf, offsets, cursor, esrc, b_out, out, nNodes);
}

// Round 12
// 129.447 us; speedup vs baseline: 1.0803x; 1.0105x over previous
//
#include <hip/hip_runtime.h>
#include <hip/hip_bf16.h>

#define NFEAT 128

typedef short bf16x8 __attribute__((ext_vector_type(8)));   // 8 bf16 as i16
typedef float f32x4  __attribute__((ext_vector_type(4)));
typedef unsigned short u16x8 __attribute__((ext_vector_type(8)));

static __device__ __forceinline__ short f2bf(float f) {
    __hip_bfloat16 h = __float2bfloat16(f);   // round-to-nearest
    return __builtin_bit_cast(short, h);
}
static __device__ __forceinline__ float bf2f(unsigned short u) {
    unsigned int x = ((unsigned int)u) << 16;
    return __builtin_bit_cast(float, x);
}

// ---------------------------------------------------------------------------
// Fast zero of counts (int4-wide).
// ---------------------------------------------------------------------------
__global__ __launch_bounds__(256) void zero_counts(int4* __restrict__ p, int n4)
{
    const int i = blockIdx.x * 256 + threadIdx.x;
    if (i < n4) p[i] = make_int4(0, 0, 0, 0);
}

// ---------------------------------------------------------------------------
// Fused GEMM: g = (relu(X @ Wm^T + bm)) @ Wo^T, bf16 out.
// 2-panel/128-row structure, 512 thr = 8 waves; wave w owns cols [16w,16w+16).
// B1/B2 reg-resident. X staged cooperatively into LDS as bf16, granule-XOR
// swizzle: elem (row,col) at row*128 + ((col>>3)^(row&15))*8 + (col&7).
// Panel-1 loads prefetched before panel-0 GEMM1; h overwrites consumed X.
// (R11 verified, 130.8 baseline — unchanged.)
// ---------------------------------------------------------------------------
__global__ __launch_bounds__(512, 4) void gemm_fused(
    const float* __restrict__ X, const short* __restrict__ Wm,
    const float* __restrict__ bm, const short* __restrict__ Wo,
    short* __restrict__ G, int n)
{
    __shared__ short xb[2][64 * NFEAT];   // 2 x 16 KB
    const int t  = threadIdx.x;
    const int w  = t >> 6;        // 0..7
    const int l  = t & 63;
    const int lr = l & 15;
    const int lk = l >> 4;
    const int row0 = blockIdx.x * 128;
    const int colw = w * 16;
    const int col  = colw + lr;

    bf16x8 b1[4], b2[4];
#pragma unroll
    for (int k0 = 0; k0 < 4; ++k0) {
        const size_t off = (size_t)col * NFEAT + k0 * 32 + lk * 8;
        b1[k0] = *(const bf16x8*)(Wm + off);
        b2[k0] = *(const bf16x8*)(Wo + off);
    }
    const float bv = bm[col];

    const int sr = t >> 4;        // 0..31
    const int cg = t & 15;

    float4 pf[4];
    {
        const int ra = min(row0 + sr, n - 1);
        const int rb = min(row0 + sr + 32, n - 1);
        const float* pa = X + (size_t)ra * NFEAT + cg * 8;
        const float* pb = X + (size_t)rb * NFEAT + cg * 8;
        pf[0] = *(const float4*)pa; pf[1] = *(const float4*)(pa + 4);
        pf[2] = *(const float4*)pb; pf[3] = *(const float4*)(pb + 4);
    }
    {
        const int g0 = cg ^ (sr & 15);
        bf16x8 v;
        v[0] = f2bf(pf[0].x); v[1] = f2bf(pf[0].y); v[2] = f2bf(pf[0].z); v[3] = f2bf(pf[0].w);
        v[4] = f2bf(pf[1].x); v[5] = f2bf(pf[1].y); v[6] = f2bf(pf[1].z); v[7] = f2bf(pf[1].w);
        *(bf16x8*)(&xb[0][sr * NFEAT + g0 * 8]) = v;
        const int r2 = sr + 32;
        const int g2 = cg ^ (r2 & 15);
        v[0] = f2bf(pf[2].x); v[1] = f2bf(pf[2].y); v[2] = f2bf(pf[2].z); v[3] = f2bf(pf[2].w);
        v[4] = f2bf(pf[3].x); v[5] = f2bf(pf[3].y); v[6] = f2bf(pf[3].z); v[7] = f2bf(pf[3].w);
        *(bf16x8*)(&xb[0][r2 * NFEAT + g2 * 8]) = v;
    }
    __syncthreads();

#pragma unroll
    for (int p = 0; p < 2; ++p) {
        short* cur = &xb[p][0];

        if (p == 0) {
            const int ra = min(row0 + 64 + sr, n - 1);
            const int rb = min(row0 + 64 + sr + 32, n - 1);
            const float* pa = X + (size_t)ra * NFEAT + cg * 8;
            const float* pb = X + (size_t)rb * NFEAT + cg * 8;
            pf[0] = *(const float4*)pa; pf[1] = *(const float4*)(pa + 4);
            pf[2] = *(const float4*)pb; pf[3] = *(const float4*)(pb + 4);
        }

        f32x4 acc[4];
#pragma unroll
        for (int rt = 0; rt < 4; ++rt) acc[rt] = (f32x4){0.f, 0.f, 0.f, 0.f};
#pragma unroll
        for (int rt = 0; rt < 4; ++rt) {
            bf16x8 a[4];
#pragma unroll
            for (int k0 = 0; k0 < 4; ++k0)
                a[k0] = *(const bf16x8*)(cur + (rt * 16 + lr) * NFEAT + ((k0 * 4 + lk) ^ lr) * 8);
#pragma unroll
            for (int k0 = 0; k0 < 4; ++k0)
                acc[rt] = __builtin_amdgcn_mfma_f32_16x16x32_bf16(a[k0], b1[k0], acc[rt], 0, 0, 0);
        }
        __syncthreads();

        {
            const int gc = col >> 3;
#pragma unroll
            for (int rt = 0; rt < 4; ++rt)
#pragma unroll
                for (int r = 0; r < 4; ++r) {
                    const int row = rt * 16 + lk * 4 + r;
                    const float v = fmaxf(acc[rt][r] + bv, 0.f);
                    cur[row * NFEAT + (gc ^ (row & 15)) * 8 + (col & 7)] = f2bf(v);
                }
        }
        if (p == 0) {
            const int g0 = cg ^ (sr & 15);
            bf16x8 v;
            v[0] = f2bf(pf[0].x); v[1] = f2bf(pf[0].y); v[2] = f2bf(pf[0].z); v[3] = f2bf(pf[0].w);
            v[4] = f2bf(pf[1].x); v[5] = f2bf(pf[1].y); v[6] = f2bf(pf[1].z); v[7] = f2bf(pf[1].w);
            *(bf16x8*)(&xb[1][sr * NFEAT + g0 * 8]) = v;
            const int r2 = sr + 32;
            const int g2 = cg ^ (r2 & 15);
            v[0] = f2bf(pf[2].x); v[1] = f2bf(pf[2].y); v[2] = f2bf(pf[2].z); v[3] = f2bf(pf[2].w);
            v[4] = f2bf(pf[3].x); v[5] = f2bf(pf[3].y); v[6] = f2bf(pf[3].z); v[7] = f2bf(pf[3].w);
            *(bf16x8*)(&xb[1][r2 * NFEAT + g2 * 8]) = v;
        }
        __syncthreads();

#pragma unroll
        for (int rt = 0; rt < 4; ++rt) {
            bf16x8 a[4];
#pragma unroll
            for (int k0 = 0; k0 < 4; ++k0)
                a[k0] = *(const bf16x8*)(cur + (rt * 16 + lr) * NFEAT + ((k0 * 4 + lk) ^ lr) * 8);
            f32x4 c0 = (f32x4){0.f, 0.f, 0.f, 0.f};
#pragma unroll
            for (int k0 = 0; k0 < 4; ++k0)
                c0 = __builtin_amdgcn_mfma_f32_16x16x32_bf16(a[k0], b2[k0], c0, 0, 0, 0);
#pragma unroll
            for (int r = 0; r < 4; ++r) {
                const int orow = row0 + p * 64 + rt * 16 + lk * 4 + r;
                if (orow < n) G[(size_t)orow * NFEAT + col] = f2bf(c0[r]);
            }
        }
    }
}

// ---------------------------------------------------------------------------
// CSR build: convert weights (first 16 blocks, 4-wide) + degree count,
// 4 edges/thread (int4 load, 4 independent atomics in flight).
// ---------------------------------------------------------------------------
__global__ __launch_bounds__(256) void convert_and_count(
    const float* __restrict__ wa, const float* __restrict__ wb,
    short* __restrict__ oa, short* __restrict__ ob,
    const int* __restrict__ dst, int* __restrict__ counts, int nE)
{
    const int tid = blockIdx.x * 256 + threadIdx.x;
    if (tid < NFEAT * NFEAT / 4) {
        const f32x4 a = *(const f32x4*)(wa + tid * 4);
        const f32x4 b = *(const f32x4*)(wb + tid * 4);
        short4 sa, sb;
        sa.x = f2bf(a[0]); sa.y = f2bf(a[1]); sa.z = f2bf(a[2]); sa.w = f2bf(a[3]);
        sb.x = f2bf(b[0]); sb.y = f2bf(b[1]); sb.z = f2bf(b[2]); sb.w = f2bf(b[3]);
        *(short4*)(oa + tid * 4) = sa;
        *(short4*)(ob + tid * 4) = sb;
    }
    const int i0 = tid * 4;
    if (i0 + 4 <= nE) {
        const int4 d4 = *(const int4*)(dst + i0);
        atomicAdd(&counts[d4.x], 1);
        atomicAdd(&counts[d4.y], 1);
        atomicAdd(&counts[d4.z], 1);
        atomicAdd(&counts[d4.w], 1);
    } else {
        for (int i = i0; i < nE; ++i) atomicAdd(&counts[dst[i]], 1);
    }
}

__global__ __launch_bounds__(256) void scan_block(
    const int* __restrict__ counts, int* __restrict__ offsets,
    int* __restrict__ blocksums, int n)
{
    __shared__ int s[256];
    const int t = threadIdx.x;
    const int i = blockIdx.x * 256 + t;
    const int v = (i < n) ? counts[i] : 0;
    s[t] = v;
    __syncthreads();
    for (int off = 1; off < 256; off <<= 1) {
        const int add = (t >= off) ? s[t - off] : 0;
        __syncthreads();
        s[t] += add;
        __syncthreads();
    }
    if (i < n) offsets[i] = s[t] - v;
    if (t == 255) blocksums[blockIdx.x] = s[255];
}

// Each block redundantly reduces blocksums[0..blockIdx) then offsets += base.
__global__ __launch_bounds__(256) void add_offsets(
    int* __restrict__ offsets, int* __restrict__ cursor,
    const int* __restrict__ blocksums, int n)
{
    __shared__ int red[256];
    int partial = 0;
    for (int j = threadIdx.x; j < blockIdx.x; j += 256) partial += blocksums[j];
    red[threadIdx.x] = partial;
    __syncthreads();
    for (int s = 128; s > 0; s >>= 1) {
        if (threadIdx.x < s) red[threadIdx.x] += red[threadIdx.x + s];
        __syncthreads();
    }
    const int base = red[0];
    const int i = blockIdx.x * 256 + threadIdx.x;
    if (i < n) {
        const int o = offsets[i] + base;
        offsets[i] = o;
        cursor[i] = o;
    }
}

// ---------------------------------------------------------------------------
// Edge fill, 4 edges/thread (int4 loads, 4 independent atomic+store chains).
// ---------------------------------------------------------------------------
__global__ __launch_bounds__(256) void fill_edges(
    const int* __restrict__ src, const int* __restrict__ dst,
    int* __restrict__ cursor, int* __restrict__ esrc, int nE)
{
    const int i0 = (blockIdx.x * 256 + threadIdx.x) * 4;
    if (i0 + 4 <= nE) {
        const int4 s4 = *(const int4*)(src + i0);
        const int4 d4 = *(const int4*)(dst + i0);
        const int p0 = atomicAdd(&cursor[d4.x], 1);
        const int p1 = atomicAdd(&cursor[d4.y], 1);
        const int p2 = atomicAdd(&cursor[d4.z], 1);
        const int p3 = atomicAdd(&cursor[d4.w], 1);
        esrc[p0] = s4.x; esrc[p1] = s4.y; esrc[p2] = s4.z; esrc[p3] = s4.w;
    } else {
        for (int i = i0; i < nE; ++i) {
            const int p = atomicAdd(&cursor[dst[i]], 1);
            esrc[p] = src[i];
        }
    }
}

// ---------------------------------------------------------------------------
// out[d] = b_out + sum_{e: dst=d} g[src[e]]   (g bf16, out f32).
// 16 lanes x ushort8 per node; 16 nodes per 256-thread block.
// Fixed 8-slot batches with clamped edge index: ALWAYS 8 independent gathers
// in flight (clamped duplicates hit cache), conditional accumulate.
// Most nodes (deg<=8, ~80%) take exactly one memory wait.
// ---------------------------------------------------------------------------
__global__ __launch_bounds__(256) void gather_sum(
    const unsigned short* __restrict__ g, const int* __restrict__ offsets,
    const int* __restrict__ cursor, const int* __restrict__ esrc,
    const float* __restrict__ bias, float* __restrict__ out, int nNodes)
{
    const int node = blockIdx.x * 16 + (threadIdx.x >> 4);
    const int lf = threadIdx.x & 15;
    if (node >= nNodes) return;

    float acc[8];
    {
        const float4 b0 = *(const float4*)(bias + lf * 8);
        const float4 b1 = *(const float4*)(bias + lf * 8 + 4);
        acc[0] = b0.x; acc[1] = b0.y; acc[2] = b0.z; acc[3] = b0.w;
        acc[4] = b1.x; acc[5] = b1.y; acc[6] = b1.z; acc[7] = b1.w;
    }

    const int beg = offsets[node];
    const int end = cursor[node];

    for (int base = beg; base < end; base += 8) {
        const int rem = end - base;           // >= 1
        u16x8 v[8];
#pragma unroll
        for (int j = 0; j < 8; ++j) {
            const int e = base + ((j < rem) ? j : (rem - 1));   // clamp
            const int s = __builtin_nontemporal_load(esrc + e);
            v[j] = *(const u16x8*)(g + (size_t)s * NFEAT + lf * 8);
        }
#pragma unroll
        for (int j = 0; j < 8; ++j) {
            if (j < rem) {
#pragma unroll
                for (int k = 0; k < 8; ++k) acc[k] += bf2f(v[j][k]);
            }
        }
    }

    float* op = out + (size_t)node * NFEAT + lf * 8;
    const f32x4 o0 = (f32x4){acc[0], acc[1], acc[2], acc[3]};
    const f32x4 o1 = (f32x4){acc[4], acc[5], acc[6], acc[7]};
    __builtin_nontemporal_store(o0, (f32x4*)op);
    __builtin_nontemporal_store(o1, (f32x4*)(op + 4));
}

extern "C" void kernel_launch(void* const* d_in, const int* in_sizes, int n_in,
                              void* d_out, int out_size, void* d_ws, size_t ws_size,
                              hipStream_t stream) {
    const float* node_feats = (const float*)d_in[0];
    const int*   src        = (const int*)d_in[1];
    const int*   dst        = (const int*)d_in[2];
    const float* W_msg      = (const float*)d_in[3];
    const float* b_msg      = (const float*)d_in[4];
    const float* W_out      = (const float*)d_in[5];
    const float* b_out      = (const float*)d_in[6];

    const int nNodes = in_sizes[0] / NFEAT;
    const int nEdges = in_sizes[1];

    float* out = (float*)d_out;

    // ws layout: gbf | wm_bf | wo_bf | counts | offsets | cursor | blocksums | esrc
    short* gbf      = (short*)d_ws;                                  // nNodes*128 bf16
    short* wm_bf    = gbf + (size_t)nNodes * NFEAT;                  // 16384 bf16
    short* wo_bf    = wm_bf + NFEAT * NFEAT;                         // 16384 bf16
    int*   counts   = (int*)(wo_bf + NFEAT * NFEAT);                 // nNodes
    int*   offsets  = counts + nNodes;                               // nNodes
    int*   cursor   = offsets + nNodes;                              // nNodes
    int*   blocksums= cursor + nNodes;                               // 512
    int*   esrc     = blocksums + 512;                               // nEdges

    const int nb1 = (nNodes + 255) / 256;   // 391
    const int nbq = (nEdges + 1023) / 1024; // 625 (4 edges/thread)
    const int ngb = (nNodes + 127) / 128;   // 782
    const int n4  = (nNodes + 3) / 4;

    // --- CSR build (+ weight conversion piggybacked) ---
    zero_counts<<<(n4 + 255) / 256, 256, 0, stream>>>((int4*)counts, n4);
    convert_and_count<<<nbq, 256, 0, stream>>>(W_msg, W_out, wm_bf, wo_bf, dst, counts, nEdges);
    scan_block<<<nb1, 256, 0, stream>>>(counts, offsets, blocksums, nNodes);
    add_offsets<<<nb1, 256, 0, stream>>>(offsets, cursor, blocksums, nNodes);
    fill_edges<<<nbq, 256, 0, stream>>>(src, dst, cursor, esrc, nEdges);

    // --- g = relu(X @ Wm^T + bm) @ Wo^T  [bf16, fused, 2-panel, 8 waves] ---
    gemm_fused<<<ngb, 512, 0, stream>>>(node_feats, wm_bf, b_msg, wo_bf, gbf, nNodes);

    // --- out[d] = b_out + sum g[src[e]] ---
    gather_sum<<<(nNodes + 15) / 16, 256, 0, stream>>>(
        (const unsigned short*)gbf, offsets, cursor, esrc, b_out, out, nNodes);
}